// Round 1
// baseline (407.787 us; speedup 1.0000x reference)
//
#include <hip/hip_runtime.h>
#include <hip/hip_bf16.h>

typedef unsigned short u16;
typedef __bf16 bf16x8 __attribute__((ext_vector_type(8)));
typedef float f32x4 __attribute__((ext_vector_type(4)));

#define AS1 __attribute__((address_space(1)))
#define AS3 __attribute__((address_space(3)))

__device__ inline u16 f2bf(float f) {
  union { float f; unsigned int u; } c; c.f = f;
  unsigned int u = c.u;
  return (u16)((u + 0x7fffu + ((u >> 16) & 1u)) >> 16);
}

// ---------------- fp32 -> bf16 conversion ----------------
__global__ __launch_bounds__(256) void cvt_f32_bf16(const float* __restrict__ in,
                                                    u16* __restrict__ out, int n4) {
  int i = blockIdx.x * 256 + threadIdx.x;
  if (i >= n4) return;
  float4 v = reinterpret_cast<const float4*>(in)[i];
  ushort4 o;
  o.x = f2bf(v.x); o.y = f2bf(v.y); o.z = f2bf(v.z); o.w = f2bf(v.w);
  reinterpret_cast<ushort4*>(out)[i] = o;
}

// ---------------- NT GEMM: C[m,n] = scale * sum_k A[m,k]*B[n,k] ----------------
// 128x128 tile, BK=32, 256 threads = 4 waves (2x2), each wave 64x64 via 4x4
// fragments of v_mfma_f32_16x16x32_bf16. global_load_lds width-16 staging.
// M, N multiples of 128; K multiple of 32 (all true for this problem).
template<bool OUT_F32>
__global__ __launch_bounds__(256) void gemm_nt(
    const u16* __restrict__ A, long lda, long sAz,
    const u16* __restrict__ B, long ldb, long sBz,
    void* __restrict__ Cv, long ldc, long sCz,
    int K, float scale)
{
  __shared__ u16 sm[2 * 128 * 32] __attribute__((aligned(16)));
  u16* sA = sm;
  u16* sB = sm + 128 * 32;

  const int t = threadIdx.x;
  const int z = blockIdx.z;
  A += (long)z * sAz;
  B += (long)z * sBz;
  const long m0 = (long)blockIdx.x * 128;
  const long n0 = (long)blockIdx.y * 128;

  const int wid = t >> 6, lane = t & 63;
  const int lhi = lane >> 4, llo = lane & 15;
  const int wr = (wid >> 1) * 64, wc = (wid & 1) * 64;
  const int srow = t >> 2;          // 0..63: tile row within 64-row half
  const int scol = (t & 3) * 8;     // bf16 column within 32-wide K slab

  f32x4 acc[4][4] = {};

  for (int k0 = 0; k0 < K; k0 += 32) {
    // stage A[128][32] and B[128][32] tiles into LDS (16B per lane, lane-linear dest)
    #pragma unroll
    for (int c = 0; c < 2; ++c) {
      const u16* ga = A + (m0 + c * 64 + srow) * lda + k0 + scol;
      const u16* gb = B + (n0 + c * 64 + srow) * ldb + k0 + scol;
      __builtin_amdgcn_global_load_lds((const AS1 void*)ga, (AS3 void*)(sA + (c * 256 + t) * 8), 16, 0, 0);
      __builtin_amdgcn_global_load_lds((const AS1 void*)gb, (AS3 void*)(sB + (c * 256 + t) * 8), 16, 0, 0);
    }
    __syncthreads();

    bf16x8 af[4], bfr[4];
    #pragma unroll
    for (int i = 0; i < 4; ++i)
      af[i] = *reinterpret_cast<const bf16x8*>(sA + (wr + i * 16 + llo) * 32 + lhi * 8);
    #pragma unroll
    for (int j = 0; j < 4; ++j)
      bfr[j] = *reinterpret_cast<const bf16x8*>(sB + (wc + j * 16 + llo) * 32 + lhi * 8);

    #pragma unroll
    for (int i = 0; i < 4; ++i)
      #pragma unroll
      for (int j = 0; j < 4; ++j)
        acc[i][j] = __builtin_amdgcn_mfma_f32_16x16x32_bf16(af[i], bfr[j], acc[i][j], 0, 0, 0);
    __syncthreads();
  }

  // epilogue: D[(lhi*4+e)][llo] per 16x16 fragment
  #pragma unroll
  for (int i = 0; i < 4; ++i) {
    #pragma unroll
    for (int e = 0; e < 4; ++e) {
      const long r = m0 + wr + i * 16 + lhi * 4 + e;
      if (OUT_F32) {
        float* C = (float*)Cv + (long)z * sCz + r * ldc + n0 + wc + llo;
        #pragma unroll
        for (int j = 0; j < 4; ++j) C[j * 16] = acc[i][j][e] * scale;
      } else {
        u16* C = (u16*)Cv + (long)z * sCz + r * ldc + n0 + wc + llo;
        #pragma unroll
        for (int j = 0; j < 4; ++j) C[j * 16] = f2bf(acc[i][j][e] * scale);
      }
    }
  }
}

// ---------------- row softmax: att fp32 [rows][1024] -> P bf16 ----------------
__global__ __launch_bounds__(256) void softmax_rows(const float* __restrict__ att,
                                                    u16* __restrict__ P) {
  const long row = blockIdx.x;
  const float4* a = reinterpret_cast<const float4*>(att + row * 1024);
  const int t = threadIdx.x;
  float4 v = a[t];
  float m = fmaxf(fmaxf(v.x, v.y), fmaxf(v.z, v.w));
  #pragma unroll
  for (int off = 32; off > 0; off >>= 1) m = fmaxf(m, __shfl_down(m, off, 64));
  __shared__ float smax[4], ssum[4];
  const int wid = t >> 6, lane = t & 63;
  if (lane == 0) smax[wid] = m;
  __syncthreads();
  m = fmaxf(fmaxf(smax[0], smax[1]), fmaxf(smax[2], smax[3]));
  float e0 = expf(v.x - m), e1 = expf(v.y - m), e2 = expf(v.z - m), e3 = expf(v.w - m);
  float s = e0 + e1 + e2 + e3;
  #pragma unroll
  for (int off = 32; off > 0; off >>= 1) s += __shfl_down(s, off, 64);
  if (lane == 0) ssum[wid] = s;
  __syncthreads();
  s = ssum[0] + ssum[1] + ssum[2] + ssum[3];
  float inv = 1.0f / s;
  ushort4 o;
  o.x = f2bf(e0 * inv); o.y = f2bf(e1 * inv); o.z = f2bf(e2 * inv); o.w = f2bf(e3 * inv);
  reinterpret_cast<ushort4*>(P + row * 1024)[t] = o;
}

extern "C" void kernel_launch(void* const* d_in, const int* in_sizes, int n_in,
                              void* d_out, int out_size, void* d_ws, size_t ws_size,
                              hipStream_t stream) {
  const float* x  = (const float*)d_in[0];
  const float* Wq = (const float*)d_in[1];
  const float* Wk = (const float*)d_in[2];
  const float* Wv = (const float*)d_in[3];
  const float* Wo = (const float*)d_in[4];

  const long Bz = 4, L = 4096, E = 1024;
  const long BL = Bz * L;                // 16384 tokens

  // workspace layout (u16 elements)
  u16* xbf  = (u16*)d_ws;                         // [16384][1024]
  u16* wqk  = xbf + BL * E;                       // [2048][1024]  (Wq rows 0-1023, Wk rows 1024-2047)
  u16* wv   = wqk + 2048L * 1024;                 // [1024][1024]
  u16* wo   = wv + 1024L * 1024;                  // [1024][1024]
  u16* qkT  = wo + 1024L * 1024;                  // [2048][16384] (qT rows 0-1023, kT rows 1024-2047)
  u16* vbuf = qkT + 2048L * 16384;                // [16384][1024]
  // aliases (lifetimes disjoint):
  u16* P    = qkT;                                // [4][1024][1024] bf16 (qkT dead after stage 2)
  u16* outb = xbf;                                // [16384][1024] bf16 (xbf dead after stage 1b)
  float* att = (float*)d_out;                     // [4][1024][1024] fp32 scratch inside d_out (16 MB < 64 MB)

  dim3 blk(256);

  // conversions
  cvt_f32_bf16<<<dim3((BL * E / 4 + 255) / 256), blk, 0, stream>>>(x, xbf, (int)(BL * E / 4));
  cvt_f32_bf16<<<dim3(1024), blk, 0, stream>>>(Wq, wqk, 1024 * 1024 / 4);
  cvt_f32_bf16<<<dim3(1024), blk, 0, stream>>>(Wk, wqk + 1024L * 1024, 1024 * 1024 / 4);
  cvt_f32_bf16<<<dim3(1024), blk, 0, stream>>>(Wv, wv, 1024 * 1024 / 4);
  cvt_f32_bf16<<<dim3(1024), blk, 0, stream>>>(Wo, wo, 1024 * 1024 / 4);

  // stage 1a: qkT = Wqk @ xbf^T    (M=2048, N=16384, K=1024) -> qT,kT
  gemm_nt<false><<<dim3(16, 128, 1), blk, 0, stream>>>(
      wqk, 1024, 0, xbf, 1024, 0, (void*)qkT, 16384, 0, 1024, 1.0f);
  // stage 1b: v = xbf @ Wv^T       (M=16384, N=1024, K=1024)
  gemm_nt<false><<<dim3(128, 8, 1), blk, 0, stream>>>(
      xbf, 1024, 0, wv, 1024, 0, (void*)vbuf, 1024, 0, 1024, 1.0f);
  // stage 2: att[b] = qT[b] @ kT[b]^T / 32   (M=N=1024, K=4096, z=4)
  gemm_nt<true><<<dim3(8, 8, 4), blk, 0, stream>>>(
      qkT, 16384, 4096, qkT + 1024L * 16384, 16384, 4096,
      (void*)att, 1024, 1024L * 1024, 4096, 1.0f / 32.0f);
  // stage 3: softmax rows -> P bf16
  softmax_rows<<<dim3(4096), blk, 0, stream>>>(att, P);
  // stage 4: out[b] = v[b] @ P[b]^T   (M=4096, N=1024, K=1024, z=4)
  gemm_nt<false><<<dim3(32, 8, 4), blk, 0, stream>>>(
      vbuf, 1024, 4096L * 1024, P, 1024, 1024L * 1024,
      (void*)outb, 1024, 4096L * 1024, 1024, 1.0f);
  // stage 5: final = out @ Wo^T    (M=16384, N=1024, K=1024) -> d_out fp32
  gemm_nt<true><<<dim3(128, 8, 1), blk, 0, stream>>>(
      outb, 1024, 0, wo, 1024, 0, d_out, 1024, 0, 1024, 1.0f);
}

// Round 2
// 280.583 us; speedup vs baseline: 1.4534x; 1.4534x over previous
//
#include <hip/hip_runtime.h>
#include <hip/hip_bf16.h>

typedef unsigned short u16;
typedef __bf16 bf16x8 __attribute__((ext_vector_type(8)));
typedef float f32x4 __attribute__((ext_vector_type(4)));

#define AS1 __attribute__((address_space(1)))
#define AS3 __attribute__((address_space(3)))

__device__ inline u16 f2bf(float f) {
  union { float f; unsigned int u; } c; c.f = f;
  unsigned int u = c.u;
  return (u16)((u + 0x7fffu + ((u >> 16) & 1u)) >> 16);
}

// ---------------- fp32 -> bf16 conversion ----------------
__global__ __launch_bounds__(256) void cvt_f32_bf16(const float* __restrict__ in,
                                                    u16* __restrict__ out, int n4) {
  int i = blockIdx.x * 256 + threadIdx.x;
  if (i >= n4) return;
  float4 v = reinterpret_cast<const float4*>(in)[i];
  ushort4 o;
  o.x = f2bf(v.x); o.y = f2bf(v.y); o.z = f2bf(v.z); o.w = f2bf(v.w);
  reinterpret_cast<ushort4*>(out)[i] = o;
}

// ---------------- 256x256 NT GEMM, BK=64, 8 waves, counted vmcnt ----------------
// C[m,n] = scale * sum_k A[m,k]*B[n,k].  M,N multiples of 256; K multiple of 64.
// LDS: 2 buffers x (A[256][64] + B[256][64]) bf16 = 128 KiB, XOR-swizzled
// (byte ^= (row&7)<<4) with pre-swizzled global source (both-sides involution).

__device__ __forceinline__ void stage_tile(const u16* __restrict__ Ag, long lda,
                                           const u16* __restrict__ Bg, long ldb,
                                           u16* sA, u16* sB, int t) {
  // 2048 chunks of 16B per matrix; thread t handles chunks r*512+t.
  // LDS dest is linear; global source column is swizzle-permuted so that the
  // swizzled read (frag_ld) sees logical data.
#pragma unroll
  for (int r = 0; r < 4; ++r) {
    const int c = r * 512 + t;
    const int row = c >> 3;
    const int s = c & 7;
    const int so = (s ^ (row & 7)) << 3;  // u16 offset within 64-wide K slab
    __builtin_amdgcn_global_load_lds((const AS1 void*)(Ag + (long)row * lda + so),
                                     (AS3 void*)(sA + c * 8), 16, 0, 0);
    __builtin_amdgcn_global_load_lds((const AS1 void*)(Bg + (long)row * ldb + so),
                                     (AS3 void*)(sB + c * 8), 16, 0, 0);
  }
}

__device__ __forceinline__ bf16x8 frag_ld(const u16* s, int row, int colb) {
  return *reinterpret_cast<const bf16x8*>(
      reinterpret_cast<const char*>(s) + row * 128 + (colb ^ ((row & 7) << 4)));
}

template<bool OUT_F32>
__global__ __launch_bounds__(512, 2) void gemm_nt256(
    const u16* __restrict__ A, long lda, long sAz,
    const u16* __restrict__ B, long ldb, long sBz,
    void* __restrict__ Cv, long ldc, long sCz,
    int K, float scale)
{
  __shared__ u16 sm[4 * 16384] __attribute__((aligned(16)));  // 128 KiB

  const int t = threadIdx.x;
  const int z = blockIdx.z;
  const long m0 = (long)blockIdx.x * 256;
  const long n0 = (long)blockIdx.y * 256;
  const u16* Abase = A + (long)z * sAz + m0 * lda;
  const u16* Bbase = B + (long)z * sBz + n0 * ldb;

  const int wid = t >> 6, lane = t & 63;
  const int lhi = lane >> 4, llo = lane & 15;
  const int wm = wid >> 2, wn = wid & 3;   // 2 x 4 waves; per-wave 128x64 output

  f32x4 acc[8][4] = {};

  // prologue: tile 0 -> buf0
  stage_tile(Abase, lda, Bbase, ldb, sm, sm + 16384, t);

  const int NT = K >> 6;
  int cur = 0;
  for (int kt = 0; kt < NT; ++kt) {
    const int knext = (kt + 1 < NT) ? ((kt + 1) << 6) : 0;  // wrap: harmless dead prefetch
    u16* nb = sm + (cur ^ 1) * 32768;
    stage_tile(Abase + knext, lda, Bbase + knext, ldb, nb, nb + 16384, t);
    // wait only the PREVIOUS tile's 8 loads; the 8 just issued stay in flight
    asm volatile("s_waitcnt vmcnt(8)" ::: "memory");
    __builtin_amdgcn_s_barrier();
    asm volatile("" ::: "memory");

    const u16* sA = sm + cur * 32768;
    const u16* sB = sA + 16384;
#pragma unroll
    for (int kk = 0; kk < 2; ++kk) {
      const int colb = (kk << 6) + (lhi << 4);
      bf16x8 af[8], bv[4];
#pragma unroll
      for (int fr = 0; fr < 8; ++fr)
        af[fr] = frag_ld(sA, wm * 128 + fr * 16 + llo, colb);
#pragma unroll
      for (int fc = 0; fc < 4; ++fc)
        bv[fc] = frag_ld(sB, wn * 64 + fc * 16 + llo, colb);
      __builtin_amdgcn_s_setprio(1);
#pragma unroll
      for (int fr = 0; fr < 8; ++fr)
#pragma unroll
        for (int fc = 0; fc < 4; ++fc)
          acc[fr][fc] = __builtin_amdgcn_mfma_f32_16x16x32_bf16(af[fr], bv[fc], acc[fr][fc], 0, 0, 0);
      __builtin_amdgcn_s_setprio(0);
    }
    asm volatile("" ::: "memory");
    __builtin_amdgcn_s_barrier();
    cur ^= 1;
  }

  // epilogue: C/D frag row=(lane>>4)*4+e, col=lane&15
#pragma unroll
  for (int fr = 0; fr < 8; ++fr) {
#pragma unroll
    for (int e = 0; e < 4; ++e) {
      const long r = m0 + wm * 128 + fr * 16 + lhi * 4 + e;
      if (OUT_F32) {
        float* C = (float*)Cv + (long)z * sCz + r * ldc + n0 + wn * 64 + llo;
#pragma unroll
        for (int fc = 0; fc < 4; ++fc) C[fc * 16] = acc[fr][fc][e] * scale;
      } else {
        u16* C = (u16*)Cv + (long)z * sCz + r * ldc + n0 + wn * 64 + llo;
#pragma unroll
        for (int fc = 0; fc < 4; ++fc) C[fc * 16] = f2bf(acc[fr][fc][e] * scale);
      }
    }
  }
}

// ---- softmax over rows of att = sum of 4 split-K partials [16][1024][1024] f32 ----
__global__ __launch_bounds__(256) void softmax_reduce4(const float* __restrict__ att,
                                                       u16* __restrict__ P) {
  const long row = blockIdx.x;            // b*1024 + r
  const long b = row >> 10;
  const int t = threadIdx.x;
  float4 v; v.x = 0.f; v.y = 0.f; v.z = 0.f; v.w = 0.f;
#pragma unroll
  for (int p = 0; p < 4; ++p) {
    const float4 u = reinterpret_cast<const float4*>(att)[((b * 4 + p) << 18) + ((row & 1023) << 8) + t];
    v.x += u.x; v.y += u.y; v.z += u.z; v.w += u.w;
  }
  float m = fmaxf(fmaxf(v.x, v.y), fmaxf(v.z, v.w));
#pragma unroll
  for (int off = 32; off > 0; off >>= 1) m = fmaxf(m, __shfl_down(m, off, 64));
  __shared__ float smax[4], ssum[4];
  const int wid = t >> 6, lane = t & 63;
  if (lane == 0) smax[wid] = m;
  __syncthreads();
  m = fmaxf(fmaxf(smax[0], smax[1]), fmaxf(smax[2], smax[3]));
  float e0 = expf(v.x - m), e1 = expf(v.y - m), e2 = expf(v.z - m), e3 = expf(v.w - m);
  float s = e0 + e1 + e2 + e3;
#pragma unroll
  for (int off = 32; off > 0; off >>= 1) s += __shfl_down(s, off, 64);
  if (lane == 0) ssum[wid] = s;
  __syncthreads();
  s = ssum[0] + ssum[1] + ssum[2] + ssum[3];
  float inv = 1.0f / s;
  ushort4 o;
  o.x = f2bf(e0 * inv); o.y = f2bf(e1 * inv); o.z = f2bf(e2 * inv); o.w = f2bf(e3 * inv);
  reinterpret_cast<ushort4*>(P + row * 1024)[t] = o;
}

extern "C" void kernel_launch(void* const* d_in, const int* in_sizes, int n_in,
                              void* d_out, int out_size, void* d_ws, size_t ws_size,
                              hipStream_t stream) {
  const float* x  = (const float*)d_in[0];
  const float* Wq = (const float*)d_in[1];
  const float* Wk = (const float*)d_in[2];
  const float* Wv = (const float*)d_in[3];
  const float* Wo = (const float*)d_in[4];

  const long Bz = 4, L = 4096, E = 1024;
  const long BL = Bz * L;                 // 16384 tokens

  // workspace layout (u16 elements)
  u16* xbf  = (u16*)d_ws;                 // [16384][1024]
  u16* wqk  = xbf + BL * E;               // [2048][1024]  (Wq rows 0-1023, Wk 1024-2047)
  u16* wv   = wqk + 2048L * 1024;         // [1024][1024]
  u16* wo   = wv + 1024L * 1024;          // [1024][1024]
  u16* qkT  = wo + 1024L * 1024;          // [2048][16384] (qT | kT, feature x token)
  u16* vbuf = qkT + 2048L * 16384;        // [16384][1024]
  // aliases (disjoint lifetimes):
  u16* P    = qkT;                        // [4][1024][1024] bf16 (qkT dead after stage 2)
  u16* outb = xbf;                        // [16384][1024] bf16 (xbf dead after stage 1b)
  float* attp = (float*)d_out;            // [16][1024][1024] f32 split-K partials (64 MB)

  dim3 b256(256), b512(512);

  // conversions
  cvt_f32_bf16<<<dim3((BL * E / 4 + 255) / 256), b256, 0, stream>>>(x, xbf, (int)(BL * E / 4));
  cvt_f32_bf16<<<dim3(1024), b256, 0, stream>>>(Wq, wqk, 1024 * 1024 / 4);
  cvt_f32_bf16<<<dim3(1024), b256, 0, stream>>>(Wk, wqk + 1024L * 1024, 1024 * 1024 / 4);
  cvt_f32_bf16<<<dim3(1024), b256, 0, stream>>>(Wv, wv, 1024 * 1024 / 4);
  cvt_f32_bf16<<<dim3(1024), b256, 0, stream>>>(Wo, wo, 1024 * 1024 / 4);

  // stage 1a: qkT = Wqk @ xbf^T   (M=2048, N=16384, K=1024)
  gemm_nt256<false><<<dim3(8, 64, 1), b512, 0, stream>>>(
      wqk, 1024, 0, xbf, 1024, 0, (void*)qkT, 16384, 0, 1024, 1.0f);
  // stage 1b: v = xbf @ Wv^T      (M=16384, N=1024, K=1024)
  gemm_nt256<false><<<dim3(64, 4, 1), b512, 0, stream>>>(
      xbf, 1024, 0, wv, 1024, 0, (void*)vbuf, 1024, 0, 1024, 1.0f);
  // stage 2: att partials, split-K: z = b*4+p, K-chunk p of batch b (offset 1024*z)
  gemm_nt256<true><<<dim3(4, 4, 16), b512, 0, stream>>>(
      qkT, 16384, 1024, qkT + 1024L * 16384, 16384, 1024,
      (void*)attp, 1024, 1L << 20, 1024, 1.0f / 32.0f);
  // stage 3: reduce partials + softmax -> P bf16
  softmax_reduce4<<<dim3(4096), b256, 0, stream>>>(attp, P);
  // stage 4: out[b] = v[b] @ P[b]^T  (M=4096, N=1024, K=1024, z=4)
  gemm_nt256<false><<<dim3(16, 4, 4), b512, 0, stream>>>(
      vbuf, 1024, 4096L * 1024, P, 1024, 1L << 20,
      (void*)outb, 1024, 4096L * 1024, 1024, 1.0f);
  // stage 5: final = out @ Wo^T   (M=16384, N=1024, K=1024) -> d_out fp32
  gemm_nt256<true><<<dim3(64, 4, 1), b512, 0, stream>>>(
      outb, 1024, 0, wo, 1024, 0, d_out, 1024, 0, 1024, 1.0f);
}

// Round 3
// 279.662 us; speedup vs baseline: 1.4581x; 1.0033x over previous
//
#include <hip/hip_runtime.h>
#include <hip/hip_bf16.h>

typedef unsigned short u16;
typedef __bf16 bf16x8 __attribute__((ext_vector_type(8)));
typedef float f32x4 __attribute__((ext_vector_type(4)));

#define AS1 __attribute__((address_space(1)))
#define AS3 __attribute__((address_space(3)))

__device__ inline u16 f2bf(float f) {
  union { float f; unsigned int u; } c; c.f = f;
  unsigned int u = c.u;
  return (u16)((u + 0x7fffu + ((u >> 16) & 1u)) >> 16);
}

// ---------------- fp32 -> bf16 conversion ----------------
__global__ __launch_bounds__(256) void cvt_f32_bf16(const float* __restrict__ in,
                                                    u16* __restrict__ out, int n4) {
  int i = blockIdx.x * 256 + threadIdx.x;
  if (i >= n4) return;
  float4 v = reinterpret_cast<const float4*>(in)[i];
  ushort4 o;
  o.x = f2bf(v.x); o.y = f2bf(v.y); o.z = f2bf(v.z); o.w = f2bf(v.w);
  reinterpret_cast<ushort4*>(out)[i] = o;
}

// ============ 256x256 NT GEMM, BK=64, 8 waves, 4-phase counted-vmcnt ============
// C[m,n] = scale * sum_k A[m,k]*B[n,k].  M,N multiples of 256; K multiple of 64,
// K/64 >= 4. LDS: 2 x (A[256][64] + B[256][64]) bf16 = 128 KiB, XOR-swizzled
// (byte ^= (row&7)<<4) with pre-swizzled global source (both-sides involution).
// Per K-tile: 4 phases; each {stage 1 half-tile || ds_read subtile; vmcnt(6);
// barrier; setprio(1); 16 MFMA; setprio(0); barrier}.  Stage slots: ph0->B0(t+1),
// ph1->A1(t+1), ph2->A0(t+2), ph3->B1(t+2); data staged at phase g is readable at
// g+4 (per-phase vmcnt(6) retires loads issued 3 phases back, then barrier).

__device__ __forceinline__ void stage_half(const u16* __restrict__ g, long ld, int k0,
                                           u16* dst, int t) {
  // one 128-row half of one matrix: 1024 chunks of 16B; thread t does 2.
#pragma unroll
  for (int i = 0; i < 2; ++i) {
    const int c = i * 512 + t;
    const int r = c >> 3;
    const int s = c & 7;
    const int col = ((s ^ (r & 7)) << 3) + k0;   // pre-swizzled global source
    __builtin_amdgcn_global_load_lds((const AS1 void*)(g + (long)r * ld + col),
                                     (AS3 void*)(dst + c * 8), 16, 0, 0);
  }
}

__device__ __forceinline__ bf16x8 frag_ld(const u16* s, int row, int colb) {
  return *reinterpret_cast<const bf16x8*>(
      reinterpret_cast<const char*>(s) + row * 128 + (colb ^ ((row & 7) << 4)));
}

#define PHASE_BAR_PRE()  do { asm volatile("s_waitcnt vmcnt(6)" ::: "memory"); \
                              __builtin_amdgcn_s_barrier(); \
                              asm volatile("" ::: "memory"); } while (0)
#define PHASE_BAR_POST() do { asm volatile("" ::: "memory"); \
                              __builtin_amdgcn_s_barrier(); \
                              asm volatile("" ::: "memory"); } while (0)

template<bool OUT_F32>
__global__ __launch_bounds__(512, 2) void gemm_nt256(
    const u16* __restrict__ A, long lda, long sAz,
    const u16* __restrict__ B, long ldb, long sBz,
    void* __restrict__ Cv, long ldc, long sCz,
    int K, float scale)
{
  __shared__ u16 sm[2 * 32768] __attribute__((aligned(16)));  // 128 KiB

  const int t = threadIdx.x;
  // T1: bijective XCD-chunked block swizzle (nwg % 8 == 0 for all our grids)
  int wg = blockIdx.x + gridDim.x * blockIdx.y;
  const int nwg = gridDim.x * gridDim.y;
  const int qq = nwg >> 3;
  wg = (wg & 7) * qq + (wg >> 3);
  const long m0 = (long)(wg % gridDim.x) * 256;
  const long n0 = (long)(wg / gridDim.x) * 256;
  const int z = blockIdx.z;
  const u16* Ab = A + (long)z * sAz + m0 * lda;
  const u16* Bb = B + (long)z * sBz + n0 * ldb;

  const int wid = t >> 6, lane = t & 63;
  const int lhi = lane >> 4, llo = lane & 15;
  const int wm = wid >> 2, wn = wid & 3;  // wave rows {wm*64, 128+wm*64}, cols {wn*32, 128+wn*32}

  f32x4 acc[2][4][2][2] = {};

  const int NT = K >> 6;

  // prologue, age order: A0(0), B1(0), B0(0), A1(0), A0(1), B1(1)
  stage_half(Ab, lda, 0, sm, t);                                  // A0(0)
  stage_half(Bb + 128 * ldb, ldb, 0, sm + 16384 + 8192, t);       // B1(0)
  stage_half(Bb, ldb, 0, sm + 16384, t);                          // B0(0)
  stage_half(Ab + 128 * lda, lda, 0, sm + 8192, t);               // A1(0)
  stage_half(Ab, lda, 64, sm + 32768, t);                         // A0(1)
  stage_half(Bb + 128 * ldb, ldb, 64, sm + 32768 + 16384 + 8192, t); // B1(1)
  asm volatile("s_waitcnt vmcnt(4)" ::: "memory");  // tile0 complete; A0(1),B1(1) in flight
  __builtin_amdgcn_s_barrier();
  asm volatile("" ::: "memory");

  for (int kt = 0; kt < NT; ++kt) {
    const int kb = kt & 1;
    u16* bc = sm + kb * 32768;          // current tile buffer
    u16* bn = sm + (kb ^ 1) * 32768;    // next tile buffer
    const u16* sAc = bc;
    const u16* sBc = bc + 16384;
    const int k1 = ((kt + 1 < NT) ? kt + 1 : 0) << 6;          // wrapped (dead) at tail
    const int k2 = ((kt + 2 < NT) ? kt + 2 : kt + 2 - NT) << 6;

    bf16x8 a[4][2], bl[2][2], bh[2][2];

    // ---- ph0: stage B0(t+1) -> bn; read A-lo + B-lo; MFMA (Alo,Blo)
    stage_half(Bb, ldb, k1, bn + 16384, t);
#pragma unroll
    for (int fr = 0; fr < 4; ++fr)
#pragma unroll
      for (int kk = 0; kk < 2; ++kk)
        a[fr][kk] = frag_ld(sAc, wm * 64 + fr * 16 + llo, (kk << 6) + (lhi << 4));
#pragma unroll
    for (int fc = 0; fc < 2; ++fc)
#pragma unroll
      for (int kk = 0; kk < 2; ++kk)
        bl[fc][kk] = frag_ld(sBc, wn * 32 + fc * 16 + llo, (kk << 6) + (lhi << 4));
    PHASE_BAR_PRE();
    __builtin_amdgcn_s_setprio(1);
#pragma unroll
    for (int fr = 0; fr < 4; ++fr)
#pragma unroll
      for (int fc = 0; fc < 2; ++fc)
#pragma unroll
        for (int kk = 0; kk < 2; ++kk)
          acc[0][fr][0][fc] = __builtin_amdgcn_mfma_f32_16x16x32_bf16(a[fr][kk], bl[fc][kk], acc[0][fr][0][fc], 0, 0, 0);
    __builtin_amdgcn_s_setprio(0);
    PHASE_BAR_POST();

    // ---- ph1: stage A1(t+1) -> bn; read B-hi; MFMA (Alo,Bhi)
    stage_half(Ab + 128 * lda, lda, k1, bn + 8192, t);
#pragma unroll
    for (int fc = 0; fc < 2; ++fc)
#pragma unroll
      for (int kk = 0; kk < 2; ++kk)
        bh[fc][kk] = frag_ld(sBc, 128 + wn * 32 + fc * 16 + llo, (kk << 6) + (lhi << 4));
    PHASE_BAR_PRE();
    __builtin_amdgcn_s_setprio(1);
#pragma unroll
    for (int fr = 0; fr < 4; ++fr)
#pragma unroll
      for (int fc = 0; fc < 2; ++fc)
#pragma unroll
        for (int kk = 0; kk < 2; ++kk)
          acc[0][fr][1][fc] = __builtin_amdgcn_mfma_f32_16x16x32_bf16(a[fr][kk], bh[fc][kk], acc[0][fr][1][fc], 0, 0, 0);
    __builtin_amdgcn_s_setprio(0);
    PHASE_BAR_POST();

    // ---- ph2: stage A0(t+2) -> bc A-lo (dead region); read A-hi; MFMA (Ahi,Bhi)
    stage_half(Ab, lda, k2, bc, t);
#pragma unroll
    for (int fr = 0; fr < 4; ++fr)
#pragma unroll
      for (int kk = 0; kk < 2; ++kk)
        a[fr][kk] = frag_ld(sAc, 128 + wm * 64 + fr * 16 + llo, (kk << 6) + (lhi << 4));
    PHASE_BAR_PRE();
    __builtin_amdgcn_s_setprio(1);
#pragma unroll
    for (int fr = 0; fr < 4; ++fr)
#pragma unroll
      for (int fc = 0; fc < 2; ++fc)
#pragma unroll
        for (int kk = 0; kk < 2; ++kk)
          acc[1][fr][1][fc] = __builtin_amdgcn_mfma_f32_16x16x32_bf16(a[fr][kk], bh[fc][kk], acc[1][fr][1][fc], 0, 0, 0);
    __builtin_amdgcn_s_setprio(0);
    PHASE_BAR_POST();

    // ---- ph3: stage B1(t+2) -> bc B-hi (dead region); MFMA (Ahi,Blo)
    stage_half(Bb + 128 * ldb, ldb, k2, bc + 16384 + 8192, t);
    PHASE_BAR_PRE();
    __builtin_amdgcn_s_setprio(1);
#pragma unroll
    for (int fr = 0; fr < 4; ++fr)
#pragma unroll
      for (int fc = 0; fc < 2; ++fc)
#pragma unroll
        for (int kk = 0; kk < 2; ++kk)
          acc[1][fr][0][fc] = __builtin_amdgcn_mfma_f32_16x16x32_bf16(a[fr][kk], bl[fc][kk], acc[1][fr][0][fc], 0, 0, 0);
    __builtin_amdgcn_s_setprio(0);
    PHASE_BAR_POST();
  }

  // epilogue: C/D frag row=(lane>>4)*4+e, col=lane&15
#pragma unroll
  for (int ah = 0; ah < 2; ++ah)
#pragma unroll
    for (int fr = 0; fr < 4; ++fr)
#pragma unroll
      for (int e = 0; e < 4; ++e) {
        const long r = m0 + ah * 128 + wm * 64 + fr * 16 + lhi * 4 + e;
#pragma unroll
        for (int bh2 = 0; bh2 < 2; ++bh2)
#pragma unroll
          for (int fc = 0; fc < 2; ++fc) {
            const long col = n0 + bh2 * 128 + wn * 32 + fc * 16 + llo;
            const float val = acc[ah][fr][bh2][fc][e] * scale;
            if (OUT_F32)
              ((float*)Cv)[(long)z * sCz + r * ldc + col] = val;
            else
              ((u16*)Cv)[(long)z * sCz + r * ldc + col] = f2bf(val);
          }
      }
}

// ---- softmax over rows of att = sum of 4 split-K partials [16][1024][1024] f32 ----
__global__ __launch_bounds__(256) void softmax_reduce4(const float* __restrict__ att,
                                                       u16* __restrict__ P) {
  const long row = blockIdx.x;            // b*1024 + r
  const long b = row >> 10;
  const int t = threadIdx.x;
  float4 v; v.x = 0.f; v.y = 0.f; v.z = 0.f; v.w = 0.f;
#pragma unroll
  for (int p = 0; p < 4; ++p) {
    const float4 u = reinterpret_cast<const float4*>(att)[((b * 4 + p) << 18) + ((row & 1023) << 8) + t];
    v.x += u.x; v.y += u.y; v.z += u.z; v.w += u.w;
  }
  float m = fmaxf(fmaxf(v.x, v.y), fmaxf(v.z, v.w));
#pragma unroll
  for (int off = 32; off > 0; off >>= 1) m = fmaxf(m, __shfl_down(m, off, 64));
  __shared__ float smax[4], ssum[4];
  const int wid = t >> 6, lane = t & 63;
  if (lane == 0) smax[wid] = m;
  __syncthreads();
  m = fmaxf(fmaxf(smax[0], smax[1]), fmaxf(smax[2], smax[3]));
  float e0 = expf(v.x - m), e1 = expf(v.y - m), e2 = expf(v.z - m), e3 = expf(v.w - m);
  float s = e0 + e1 + e2 + e3;
#pragma unroll
  for (int off = 32; off > 0; off >>= 1) s += __shfl_down(s, off, 64);
  if (lane == 0) ssum[wid] = s;
  __syncthreads();
  s = ssum[0] + ssum[1] + ssum[2] + ssum[3];
  float inv = 1.0f / s;
  ushort4 o;
  o.x = f2bf(e0 * inv); o.y = f2bf(e1 * inv); o.z = f2bf(e2 * inv); o.w = f2bf(e3 * inv);
  reinterpret_cast<ushort4*>(P + row * 1024)[t] = o;
}

extern "C" void kernel_launch(void* const* d_in, const int* in_sizes, int n_in,
                              void* d_out, int out_size, void* d_ws, size_t ws_size,
                              hipStream_t stream) {
  const float* x  = (const float*)d_in[0];
  const float* Wq = (const float*)d_in[1];
  const float* Wk = (const float*)d_in[2];
  const float* Wv = (const float*)d_in[3];
  const float* Wo = (const float*)d_in[4];

  const long Bz = 4, L = 4096, E = 1024;
  const long BL = Bz * L;                 // 16384 tokens

  // workspace layout (u16 elements)
  u16* xbf  = (u16*)d_ws;                 // [16384][1024]
  u16* wqk  = xbf + BL * E;               // [2048][1024]  (Wq rows 0-1023, Wk 1024-2047)
  u16* wv   = wqk + 2048L * 1024;         // [1024][1024]
  u16* wo   = wv + 1024L * 1024;          // [1024][1024]
  u16* qkT  = wo + 1024L * 1024;          // [2048][16384] (qT | kT, feature x token)
  u16* vbuf = qkT + 2048L * 16384;        // [16384][1024]
  // aliases (disjoint lifetimes):
  u16* P    = qkT;                        // [4][1024][1024] bf16 (qkT dead after stage 2)
  u16* outb = xbf;                        // [16384][1024] bf16 (xbf dead after stage 1b)
  float* attp = (float*)d_out;            // [16][1024][1024] f32 split-K partials (64 MB)

  dim3 b256(256), b512(512);

  // conversions
  cvt_f32_bf16<<<dim3((BL * E / 4 + 255) / 256), b256, 0, stream>>>(x, xbf, (int)(BL * E / 4));
  cvt_f32_bf16<<<dim3(1024), b256, 0, stream>>>(Wq, wqk, 1024 * 1024 / 4);
  cvt_f32_bf16<<<dim3(1024), b256, 0, stream>>>(Wk, wqk + 1024L * 1024, 1024 * 1024 / 4);
  cvt_f32_bf16<<<dim3(1024), b256, 0, stream>>>(Wv, wv, 1024 * 1024 / 4);
  cvt_f32_bf16<<<dim3(1024), b256, 0, stream>>>(Wo, wo, 1024 * 1024 / 4);

  // stage 1a: qkT = Wqk @ xbf^T   (M=2048, N=16384, K=1024)
  gemm_nt256<false><<<dim3(8, 64, 1), b512, 0, stream>>>(
      wqk, 1024, 0, xbf, 1024, 0, (void*)qkT, 16384, 0, 1024, 1.0f);
  // stage 1b: v = xbf @ Wv^T      (M=16384, N=1024, K=1024)
  gemm_nt256<false><<<dim3(64, 4, 1), b512, 0, stream>>>(
      xbf, 1024, 0, wv, 1024, 0, (void*)vbuf, 1024, 0, 1024, 1.0f);
  // stage 2: att partials, split-K: z = b*4+p, K-chunk p of batch b (offset 1024*z)
  gemm_nt256<true><<<dim3(4, 4, 16), b512, 0, stream>>>(
      qkT, 16384, 1024, qkT + 1024L * 16384, 16384, 1024,
      (void*)attp, 1024, 1L << 20, 1024, 1.0f / 32.0f);
  // stage 3: reduce partials + softmax -> P bf16
  softmax_reduce4<<<dim3(4096), b256, 0, stream>>>(attp, P);
  // stage 4: out[b] = v[b] @ P[b]^T  (M=4096, N=1024, K=1024, z=4)
  gemm_nt256<false><<<dim3(16, 4, 4), b512, 0, stream>>>(
      vbuf, 1024, 4096L * 1024, P, 1024, 1L << 20,
      (void*)outb, 1024, 4096L * 1024, 1024, 1.0f);
  // stage 5: final = out @ Wo^T   (M=16384, N=1024, K=1024) -> d_out fp32
  gemm_nt256<true><<<dim3(64, 4, 1), b512, 0, stream>>>(
      outb, 1024, 0, wo, 1024, 0, d_out, 1024, 0, 1024, 1.0f);
}